// Round 12
// baseline (191.973 us; speedup 1.0000x reference)
//
#include <hip/hip_runtime.h>

typedef unsigned short u16;
typedef unsigned int u32;
typedef unsigned long long u64;

typedef __bf16 bf16x8 __attribute__((ext_vector_type(8)));
typedef float f32x4 __attribute__((ext_vector_type(4)));

#define LOG2E 1.44269504088896340736f

__device__ __forceinline__ float b2f(u16 u) {
    u32 x = ((u32)u) << 16;
    return __builtin_bit_cast(float, x);
}
__device__ __forceinline__ u16 f2b(float f) {
    u32 u = __builtin_bit_cast(u32, f);
    u32 r = (u + 0x7fffu + ((u >> 16) & 1u)) >> 16;
    return (u16)r;
}
__device__ __forceinline__ float ld(const void* p, int i, bool bf) {
    return bf ? b2f(((const u16*)p)[i]) : ((const float*)p)[i];
}
__device__ __forceinline__ bool detect_bf16(const void* masks) {
    return ((const u16*)masks)[0] != 0;
}
__device__ __forceinline__ f32x4 mfma16(bf16x8 a, bf16x8 b, f32x4 c) {
    return __builtin_amdgcn_mfma_f32_16x16x32_bf16(a, b, c, 0, 0, 0);
}

// ---------------- device-global scratch ----------------
__device__ __attribute__((aligned(256))) u32  g_adjm[16384 * 16];   // bitmask
__device__ __attribute__((aligned(256))) u16  g_BT1[512 * 128];     // W_heads^T [h*64+o][k]
__device__ __attribute__((aligned(256))) u16  g_BT2[128 * 512];     // W_out^T
__device__ __attribute__((aligned(256))) u16  g_Xc[32 * 512 * 128]; // bf16 graph_inf (f32 case)
__device__ __attribute__((aligned(256))) u16  g_Wh1[512 * 16384];   // Wh1T: [h*64+o][b*512+n]
__device__ __attribute__((aligned(256))) u16  g_xb[16384 * 512];    // concat ELU output
__device__ __attribute__((aligned(256))) u16  g_Wh2[16384 * 128];   // out-layer features
__device__ __attribute__((aligned(256))) float g_s1a[131072];       // x log2e
__device__ __attribute__((aligned(256))) float g_s2a[131072];
__device__ __attribute__((aligned(256))) float g_s1b[16384];        // x log2e
__device__ __attribute__((aligned(256))) float g_s2b[16384];
__device__ __attribute__((aligned(256))) u16  g_fc1T[256 * 192];
__device__ __attribute__((aligned(256))) u16  g_fc2T[256 * 256];
__device__ __attribute__((aligned(256))) u16  g_fc3T[512 * 256];
__device__ __attribute__((aligned(256))) u16  g_Ahi[32 * 192];
__device__ __attribute__((aligned(256))) u16  g_Alo[32 * 192];
__device__ __attribute__((aligned(256))) u16  g_H1hi[32 * 256];
__device__ __attribute__((aligned(256))) u16  g_H1lo[32 * 256];
__device__ __attribute__((aligned(256))) u16  g_H2hi[32 * 256];
__device__ __attribute__((aligned(256))) u16  g_H2lo[32 * 256];
__device__ __attribute__((aligned(256))) float g_logits[32 * 512];

// ---------------------------------------------------------------------------
// PREP: adj -> bitmask (ballot-free, 8-deep MLP); weight transposes; Xc cast.
// ---------------------------------------------------------------------------
__global__ __launch_bounds__(256) void prep_kernel(
    const int* __restrict__ adj, const void* __restrict__ Whd,
    const void* __restrict__ Wo, const void* __restrict__ Xin,
    const void* __restrict__ fc1w, const void* __restrict__ fc2w,
    const void* __restrict__ fc3w, const void* __restrict__ masks)
{
    const bool bf = detect_bf16(masks);
    const int blk = blockIdx.x;
    const int tid = threadIdx.x;
    if (blk < 1024) {
        int id = blk * 256 + tid;
        int row = id >> 4, w = id & 15;
        const int4* p = (const int4*)(adj + row * 512 + w * 32);
        int4 v[8];
        #pragma unroll
        for (int s = 0; s < 8; ++s) v[s] = p[s];
        u32 word = 0;
        #pragma unroll
        for (int s = 0; s < 8; ++s) {
            u32 nib = (v[s].x > 0 ? 1u : 0u) | (v[s].y > 0 ? 2u : 0u) |
                      (v[s].z > 0 ? 4u : 0u) | (v[s].w > 0 ? 8u : 0u);
            word |= nib << (4 * s);
        }
        g_adjm[id] = word;
    } else if (blk < 1028) {
        int base = (blk - 1024) * 16384;
        for (int e = base + tid; e < base + 16384; e += 256) {
            int n = e >> 7, k = e & 127;           // BT1[n][k] = W_heads[h][k][o]
            g_BT1[e] = f2b(ld(Whd, (n >> 6) * 8192 + k * 64 + (n & 63), bf));
        }
    } else if (blk < 1032) {
        int base = (blk - 1028) * 16384;
        for (int e = base + tid; e < base + 16384; e += 256) {
            int n = e >> 9, k = e & 511;           // BT2[n][k] = W_out[k][n]
            g_BT2[e] = f2b(ld(Wo, k * 128 + n, bf));
        }
    } else if (blk < 1288) {
        if (!bf) {
            int base = (blk - 1032) * 8192;
            for (int e = base + tid; e < base + 8192; e += 256)
                g_Xc[e] = f2b(((const float*)Xin)[e]);
        }
    } else if (blk < 1294) {                       // fc1T: 256x192
        int base = (blk - 1288) * 8192;
        for (int e = base + tid; e < base + 8192; e += 256) {
            int n = e / 192, k = e - n * 192;
            g_fc1T[e] = f2b(ld(fc1w, k * 256 + n, bf));
        }
    } else if (blk < 1302) {                       // fc2T: 256x256
        int base = (blk - 1294) * 8192;
        for (int e = base + tid; e < base + 8192; e += 256) {
            int n = e >> 8, k = e & 255;
            g_fc2T[e] = f2b(ld(fc2w, k * 256 + n, bf));
        }
    } else {                                       // fc3T: 512x256
        int base = (blk - 1302) * 8192;
        for (int e = base + tid; e < base + 8192; e += 256) {
            int n = e >> 8, k = e & 255;
            g_fc3T[e] = f2b(ld(fc3w, k * 512 + n, bf));
        }
    }
}

// ---------------------------------------------------------------------------
// GEMM1T: Wh1T[512][16384] = BT1[512x128] @ Xc^T. s1a/s2a epilogue (x log2e).
// (R9-verified kernel, restored.)
// ---------------------------------------------------------------------------
__global__ __launch_bounds__(256, 2) void gemm1_kernel(
    const void* __restrict__ Xin, const void* __restrict__ a_heads,
    const void* __restrict__ masks)
{
    __shared__ __attribute__((aligned(16))) u16 Asl[128 * 72];
    __shared__ __attribute__((aligned(16))) u16 Bsl[128 * 72];
    const bool bf = detect_bf16(masks);
    const u16* Bsrc = bf ? (const u16*)Xin : g_Xc;
    const int tid = threadIdx.x;
    const int wave = tid >> 6, lane = tid & 63;
    const int wr = wave >> 1, wc = wave & 1;
    const int c = lane & 15, q = lane >> 4;
    const int tm = blockIdx.x * 128, tn = blockIdx.y * 128;
    const int srow = tid >> 1, sh = (tid & 1) * 32;
    f32x4 acc[4][4] = {};
    for (int kc = 0; kc < 128; kc += 64) {
        __syncthreads();
        const u16* Ag = g_BT1 + (tm + srow) * 128 + kc + sh;
        const u16* Bg = Bsrc + (tn + srow) * 128 + kc + sh;
        #pragma unroll
        for (int s = 0; s < 4; ++s) {
            *(uint4*)&Asl[srow * 72 + sh + 8 * s] = *(const uint4*)(Ag + 8 * s);
            *(uint4*)&Bsl[srow * 72 + sh + 8 * s] = *(const uint4*)(Bg + 8 * s);
        }
        __syncthreads();
        #pragma unroll
        for (int kt = 0; kt < 2; ++kt) {
            bf16x8 af[4], bfr[4];
            #pragma unroll
            for (int rt = 0; rt < 4; ++rt)
                af[rt] = *(const bf16x8*)&Asl[(wr * 64 + rt * 16 + c) * 72 + kt * 32 + q * 8];
            #pragma unroll
            for (int ct = 0; ct < 4; ++ct)
                bfr[ct] = *(const bf16x8*)&Bsl[(wc * 64 + ct * 16 + c) * 72 + kt * 32 + q * 8];
            #pragma unroll
            for (int rt = 0; rt < 4; ++rt)
                #pragma unroll
                for (int ct = 0; ct < 4; ++ct)
                    acc[rt][ct] = mfma16(af[rt], bfr[ct], acc[rt][ct]);
        }
    }
    #pragma unroll
    for (int rt = 0; rt < 4; ++rt)
        #pragma unroll
        for (int ct = 0; ct < 4; ++ct)
            #pragma unroll
            for (int i = 0; i < 4; ++i) {
                int r = tm + wr * 64 + rt * 16 + q * 4 + i;
                int col = tn + wc * 64 + ct * 16 + c;
                g_Wh1[r * 16384 + col] = f2b(acc[rt][ct][i]);
            }
    const int hh = blockIdx.x * 2 + wr;
    const int b = tn >> 9;
    const int nbase = (tn & 511) + wc * 64;
    float a1v[4][4], a2v[4][4];
    #pragma unroll
    for (int rt = 0; rt < 4; ++rt)
        #pragma unroll
        for (int i = 0; i < 4; ++i) {
            int o = rt * 16 + q * 4 + i;
            a1v[rt][i] = ld(a_heads, hh * 128 + o, bf);
            a2v[rt][i] = ld(a_heads, hh * 128 + 64 + o, bf);
        }
    #pragma unroll
    for (int ct = 0; ct < 4; ++ct) {
        float p1 = 0.f, p2 = 0.f;
        #pragma unroll
        for (int rt = 0; rt < 4; ++rt)
            #pragma unroll
            for (int i = 0; i < 4; ++i) {
                p1 += acc[rt][ct][i] * a1v[rt][i];
                p2 += acc[rt][ct][i] * a2v[rt][i];
            }
        p1 += __shfl_xor(p1, 16); p1 += __shfl_xor(p1, 32);
        p2 += __shfl_xor(p2, 16); p2 += __shfl_xor(p2, 32);
        if (lane < 16) {
            int n = nbase + ct * 16 + lane;
            g_s1a[(b * 8 + hh) * 512 + n] = p1 * LOG2E;
            g_s2a[(b * 8 + hh) * 512 + n] = p2 * LOG2E;
        }
    }
}

// ---------------------------------------------------------------------------
// ATT1 v6: 512 blocks x 512 threads; block = (b,h,half). LDS = 70.5 KB ->
// 2 blocks/CU co-resident (the fused R10/R11 kernel's 139 KB LDS could never
// have cross-block overlap -- that was its ~4x stall factor). Both halves of
// one (b,h) land on the same XCD (blk%8 preserved by the +256 half offset).
// Wave owns 32 rows (2 groups); scores via factored exponentials; bfrags via
// immediate-offset ds_read_b128 from the staged WhL (stride 520).
// ---------------------------------------------------------------------------
__global__ __launch_bounds__(512, 4) void att1_kernel(const void* __restrict__ masks)
{
    __shared__ __attribute__((aligned(16))) u16 WhL[64 * 520];
    __shared__ float E2s[512];
    __shared__ float E2ps[512];

    const bool bf = detect_bf16(masks);
    const int tid = threadIdx.x;
    const int w = tid >> 6, lane = tid & 63;
    const int c = lane & 15, q = lane >> 4;
    const int bh = blockIdx.x & 255;
    const int half = blockIdx.x >> 8;
    const int h = bh & 7;
    const int b = bh >> 3;

    const u16* wt = g_Wh1 + (u32)(h * 64) * 16384 + b * 512;
    {
        // stage 64 rows x 512 u16, coalesced: 8 threads per row, 128 B each
        int r = tid >> 3, seg = tid & 7;
        const u16* src = wt + r * 16384 + seg * 64;
        u16* dst = &WhL[r * 520 + seg * 64];
        *(uint4*)dst = *(const uint4*)src;
        *(uint4*)(dst + 8) = *(const uint4*)(src + 8);
        *(uint4*)(dst + 16) = *(const uint4*)(src + 16);
        *(uint4*)(dst + 24) = *(const uint4*)(src + 24);
        *(uint4*)(dst + 32) = *(const uint4*)(src + 32);
        *(uint4*)(dst + 40) = *(const uint4*)(src + 40);
        *(uint4*)(dst + 48) = *(const uint4*)(src + 48);
        *(uint4*)(dst + 56) = *(const uint4*)(src + 56);
        float s2v = g_s2a[(b * 8 + h) * 512 + tid];
        E2s[tid]  = exp2f(s2v);
        E2ps[tid] = exp2f(0.2f * s2v);
    }
    __syncthreads();

    const u32* adjb = g_adjm + b * 8192;
    const u32 bword = (c == 0) ? 0x3F803F80u : 0u;
    const uint4 bq = {bword, bword, bword, bword};
    const bf16x8 bone = __builtin_bit_cast(bf16x8, bq);

    // wave w owns rows half*256 + w*32 + g*16 + c, g in {0,1}
    const int rbase = half * 256 + w * 32;
    float E1[2], E1p[2];
    #pragma unroll
    for (int g = 0; g < 2; ++g) {
        float s1v = g_s1a[(b * 8 + h) * 512 + rbase + g * 16 + c];
        E1[g]  = exp2f(s1v);
        E1p[g] = exp2f(0.2f * s1v);
    }

    f32x4 acc[2][4] = {};
    f32x4 acc1[2] = {};
    const u16* lbase = &WhL[c * 520 + q * 8];

    for (int kc = 0; kc < 4; ++kc) {
        union { uint4 v; u32 a[4]; } wq[2];
        #pragma unroll
        for (int g = 0; g < 2; ++g)
            wq[g].v = *(const uint4*)(adjb + (rbase + g * 16 + c) * 16 + kc * 4);
        #pragma unroll
        for (int tl = 0; tl < 4; ++tl) {
            const int jb = kc * 128 + tl * 32 + q * 8;
            union { float4 v[2]; float f[8]; } e2r, e2pr;
            e2r.v[0]  = *(const float4*)&E2s[jb];
            e2r.v[1]  = *(const float4*)&E2s[jb + 4];
            e2pr.v[0] = *(const float4*)&E2ps[jb];
            e2pr.v[1] = *(const float4*)&E2ps[jb + 4];
            bf16x8 bfrag[4];
            #pragma unroll
            for (int nt = 0; nt < 4; ++nt)
                bfrag[nt] = *(const bf16x8*)(lbase + nt * 16 * 520 + kc * 128 + tl * 32);
            #pragma unroll
            for (int g = 0; g < 2; ++g) {
                u32 wbits = wq[g].a[tl] >> (q * 8);
                u32 pk[4];
                #pragma unroll
                for (int pi = 0; pi < 4; ++pi) {
                    float z0 = fmaxf(E1[g] * e2r.f[2 * pi],     E1p[g] * e2pr.f[2 * pi]);
                    float z1 = fmaxf(E1[g] * e2r.f[2 * pi + 1], E1p[g] * e2pr.f[2 * pi + 1]);
                    z0 = ((wbits >> (2 * pi)) & 1u) ? z0 : 0.f;
                    z1 = ((wbits >> (2 * pi + 1)) & 1u) ? z1 : 0.f;
                    pk[pi] = __builtin_amdgcn_perm(__builtin_bit_cast(u32, z1),
                                                   __builtin_bit_cast(u32, z0),
                                                   0x07060302u);
                }
                uint4 pkv = {pk[0], pk[1], pk[2], pk[3]};
                bf16x8 pv = __builtin_bit_cast(bf16x8, pkv);
                acc1[g] = mfma16(pv, bone, acc1[g]);
                #pragma unroll
                for (int nt = 0; nt < 4; ++nt)
                    acc[g][nt] = mfma16(pv, bfrag[nt], acc[g][nt]);
            }
        }
    }
    #pragma unroll
    for (int g = 0; g < 2; ++g) {
        const int R = rbase + g * 16;
        #pragma unroll
        for (int i = 0; i < 4; ++i) {
            float lr = __shfl(acc1[g][i], (lane & 48));
            float invr = (lr == 0.f) ? (1.f / 512.f) : (1.f / lr);
            const int row = R + q * 4 + i;
            float mk = ld(masks, b * 512 + row, bf);
            #pragma unroll
            for (int nt = 0; nt < 4; ++nt) {
                float v = acc[g][nt][i] * invr * mk;
                float o = v > 0.f ? v : (__expf(v) - 1.f);
                g_xb[(b * 512 + row) * 512 + h * 64 + nt * 16 + c] = f2b(o);
            }
        }
    }
}

// ---------------------------------------------------------------------------
// GEMM2: Wh2[16384x128] = xb @ BT2^T. BM=64, grid 256. s1b/s2b epilogue.
// ---------------------------------------------------------------------------
__global__ __launch_bounds__(256, 2) void gemm2_kernel(
    const void* __restrict__ a_out, const void* __restrict__ masks)
{
    __shared__ __attribute__((aligned(16))) u16 Asl[64 * 72];
    __shared__ __attribute__((aligned(16))) u16 Bsl[128 * 72];
    const int tid = threadIdx.x;
    const int w = tid >> 6, lane = tid & 63;
    const int c = lane & 15, q = lane >> 4;
    const int tm = blockIdx.x * 64;
    const int rowA = tid >> 2, shA = (tid & 3) * 16;
    const int rowB = tid >> 1, shB = (tid & 1) * 32;
    f32x4 acc[8] = {};
    for (int kc = 0; kc < 512; kc += 64) {
        __syncthreads();
        const u16* Ag = g_xb + (tm + rowA) * 512 + kc + shA;
        *(uint4*)&Asl[rowA * 72 + shA] = *(const uint4*)Ag;
        *(uint4*)&Asl[rowA * 72 + shA + 8] = *(const uint4*)(Ag + 8);
        const u16* Bg = g_BT2 + rowB * 512 + kc + shB;
        #pragma unroll
        for (int s = 0; s < 4; ++s)
            *(uint4*)&Bsl[rowB * 72 + shB + 8 * s] = *(const uint4*)(Bg + 8 * s);
        __syncthreads();
        #pragma unroll
        for (int kt = 0; kt < 2; ++kt) {
            bf16x8 av = *(const bf16x8*)&Asl[(w * 16 + c) * 72 + kt * 32 + q * 8];
            #pragma unroll
            for (int ct = 0; ct < 8; ++ct) {
                bf16x8 bv = *(const bf16x8*)&Bsl[(ct * 16 + c) * 72 + kt * 32 + q * 8];
                acc[ct] = mfma16(av, bv, acc[ct]);
            }
        }
    }
    const bool bf = detect_bf16(masks);
    float a1v[8], a2v[8];
    #pragma unroll
    for (int ct = 0; ct < 8; ++ct) {
        a1v[ct] = ld(a_out, ct * 16 + c, bf);
        a2v[ct] = ld(a_out, 128 + ct * 16 + c, bf);
    }
    #pragma unroll
    for (int i = 0; i < 4; ++i) {
        float p1 = 0.f, p2 = 0.f;
        #pragma unroll
        for (int ct = 0; ct < 8; ++ct) {
            p1 += acc[ct][i] * a1v[ct];
            p2 += acc[ct][i] * a2v[ct];
        }
        #pragma unroll
        for (int off = 1; off < 16; off <<= 1) {
            p1 += __shfl_xor(p1, off);
            p2 += __shfl_xor(p2, off);
        }
        if (c == 0) {
            int m = tm + w * 16 + q * 4 + i;
            g_s1b[m] = p1 * LOG2E;
            g_s2b[m] = p2 * LOG2E;
        }
    }
    #pragma unroll
    for (int ct = 0; ct < 8; ++ct)
        #pragma unroll
        for (int i = 0; i < 4; ++i) {
            int m = tm + w * 16 + q * 4 + i;
            g_Wh2[m * 128 + ct * 16 + c] = f2b(acc[ct][i]);
        }
}

// ---------------------------------------------------------------------------
// FIN_ATT: block per b. Selected-row attention; writes hi/lo MLP input.
// ---------------------------------------------------------------------------
__global__ __launch_bounds__(256) void fin_att(
    const void* __restrict__ masks, const int* __restrict__ node_order,
    const void* __restrict__ workv, const void* __restrict__ subtaskv)
{
    __shared__ float att[512];
    __shared__ float parts[16][128];
    __shared__ float redl[4];

    const bool bf = detect_bf16(masks);
    const int b = blockIdx.x, t = threadIdx.x;
    const int lane = t & 63, wv = t >> 6;
    const int istar = node_order[b];

    const float s1v = g_s1b[b * 512 + istar];
    const u32* arow = g_adjm + (b * 512 + istar) * 16;
    float ssum = 0.f;
    #pragma unroll
    for (int rep = 0; rep < 2; ++rep) {
        int j = t + rep * 256;
        float e = s1v + g_s2b[b * 512 + j];
        e = fmaxf(e, 0.2f * e);
        float ex = ((arow[j >> 5] >> (j & 31)) & 1u) ? exp2f(e) : 0.f;
        att[j] = ex;
        ssum += ex;
    }
    for (int off = 1; off < 64; off <<= 1) ssum += __shfl_xor(ssum, off);
    if (lane == 0) redl[wv] = ssum;
    __syncthreads();
    float tot = redl[0] + redl[1] + redl[2] + redl[3];
    bool uni = (tot == 0.f);
    float inv = uni ? (1.f / 512.f) : (1.f / tot);

    const int og = t & 15, jg = t >> 4;
    float acc[8] = {};
    const u16* base = g_Wh2 + (b * 512 + jg * 32) * 128 + og * 8;
    #pragma unroll 8
    for (int j0 = 0; j0 < 32; ++j0) {
        float wgt = uni ? 1.f : att[jg * 32 + j0];
        union { u16 u[8]; uint4 v; } z;
        z.v = *(const uint4*)(base + j0 * 128);
        #pragma unroll
        for (int i = 0; i < 8; ++i) acc[i] += wgt * b2f(z.u[i]);
    }
    #pragma unroll
    for (int i = 0; i < 8; ++i) parts[jg][og * 8 + i] = acc[i];
    __syncthreads();
    float mk = ld(masks, b * 512 + istar, bf);
    if (t < 128) {
        float s = 0.f;
        #pragma unroll
        for (int jj = 0; jj < 16; ++jj) s += parts[jj][t];
        s *= inv * mk * mk;
        u16 hi = f2b(s);
        g_Ahi[b * 192 + t] = hi;
        g_Alo[b * 192 + t] = f2b(s - b2f(hi));
    } else if (t < 160) {
        g_Ahi[b * 192 + t] = bf ? ((const u16*)workv)[b * 32 + t - 128]
                                : f2b(((const float*)workv)[b * 32 + t - 128]);
        g_Alo[b * 192 + t] = 0;
    } else if (t < 192) {
        g_Ahi[b * 192 + t] = bf ? ((const u16*)subtaskv)[b * 32 + t - 160]
                                : f2b(((const float*)subtaskv)[b * 32 + t - 160]);
        g_Alo[b * 192 + t] = 0;
    }
}

// ---------------------------------------------------------------------------
// MLP layer body: wave w owns 16 output cols; direct global loads, no LDS.
// Wrappers bind device-global scratch IN DEVICE CODE.
// ---------------------------------------------------------------------------
template<int K, int NOUT, bool RELU>
__device__ __forceinline__ void mlp_body(
    const u16* __restrict__ Ahi, const u16* __restrict__ Alo,
    const u16* __restrict__ WT, const void* __restrict__ bias,
    u16* __restrict__ Ohi, u16* __restrict__ Olo, float* __restrict__ Of,
    const void* __restrict__ masks)
{
    const bool bf = detect_bf16(masks);
    const int t = threadIdx.x, w = t >> 6, lane = t & 63;
    const int c = lane & 15, q = lane >> 4;
    const int col = blockIdx.x * 64 + w * 16 + c;

    const u16* wp  = WT + col * K + q * 8;
    const u16* ahp = Ahi + c * K + q * 8;
    const u16* alp = Alo + c * K + q * 8;

    f32x4 acc0 = {}, acc1 = {};
    #pragma unroll
    for (int kt = 0; kt < K / 32; ++kt) {
        bf16x8 bw  = *(const bf16x8*)(wp + kt * 32);
        bf16x8 ah0 = *(const bf16x8*)(ahp + kt * 32);
        bf16x8 al0 = *(const bf16x8*)(alp + kt * 32);
        bf16x8 ah1 = *(const bf16x8*)(ahp + 16 * K + kt * 32);
        bf16x8 al1 = *(const bf16x8*)(alp + 16 * K + kt * 32);
        acc0 = mfma16(ah0, bw, acc0);
        acc0 = mfma16(al0, bw, acc0);
        acc1 = mfma16(ah1, bw, acc1);
        acc1 = mfma16(al1, bw, acc1);
    }
    float bs = ld(bias, col, bf);
    #pragma unroll
    for (int mt = 0; mt < 2; ++mt) {
        f32x4 a = mt ? acc1 : acc0;
        #pragma unroll
        for (int i = 0; i < 4; ++i) {
            int m = mt * 16 + q * 4 + i;
            float v = a[i] + bs;
            if (RELU) {
                v = fmaxf(v, 0.f);
                u16 hi = f2b(v);
                Ohi[m * NOUT + col] = hi;
                Olo[m * NOUT + col] = f2b(v - b2f(hi));
            } else {
                Of[m * NOUT + col] = v;
            }
        }
    }
}

__global__ __launch_bounds__(256) void mlp1_kernel(const void* bias, const void* masks) {
    mlp_body<192, 256, true>(g_Ahi, g_Alo, g_fc1T, bias, g_H1hi, g_H1lo, nullptr, masks);
}
__global__ __launch_bounds__(256) void mlp2_kernel(const void* bias, const void* masks) {
    mlp_body<256, 256, true>(g_H1hi, g_H1lo, g_fc2T, bias, g_H2hi, g_H2lo, nullptr, masks);
}
__global__ __launch_bounds__(256) void mlp3_kernel(const void* bias, const void* masks) {
    mlp_body<256, 512, false>(g_H2hi, g_H2lo, g_fc3T, bias, nullptr, nullptr, g_logits, masks);
}

// ---------------------------------------------------------------------------
// SOFTMAX: 32 blocks (one per batch row) x 64 lanes; 8 logits per lane.
// ---------------------------------------------------------------------------
__global__ __launch_bounds__(64) void softmax_kernel(
    const void* __restrict__ masks, void* __restrict__ out)
{
    const bool bf = detect_bf16(masks);
    const int row = blockIdx.x, lane = threadIdx.x;
    const float* lp = g_logits + row * 512 + lane * 8;
    float v[8];
    *(float4*)&v[0] = *(const float4*)lp;
    *(float4*)&v[4] = *(const float4*)(lp + 4);
    float mx = v[0];
    #pragma unroll
    for (int i = 1; i < 8; ++i) mx = fmaxf(mx, v[i]);
    for (int off = 1; off < 64; off <<= 1) mx = fmaxf(mx, __shfl_xor(mx, off));
    float e[8];
    float s = 0.f;
    #pragma unroll
    for (int i = 0; i < 8; ++i) { e[i] = __expf(v[i] - mx); s += e[i]; }
    for (int off = 1; off < 64; off <<= 1) s += __shfl_xor(s, off);
    float inv = 1.f / s;
    if (bf) {
        u16* o = (u16*)out + row * 512 + lane * 8;
        #pragma unroll
        for (int i = 0; i < 8; ++i) o[i] = f2b(e[i] * inv);
    } else {
        float* o = (float*)out + row * 512 + lane * 8;
        #pragma unroll
        for (int i = 0; i < 8; ++i) o[i] = e[i] * inv;
    }
}

// ---------------------------------------------------------------------------
extern "C" void kernel_launch(void* const* d_in, const int* in_sizes, int n_in,
                              void* d_out, int out_size, void* d_ws, size_t ws_size,
                              hipStream_t stream)
{
    const void* graph_inf    = d_in[0];
    const int*  graph_matrix = (const int*)d_in[1];
    const void* masks        = d_in[2];
    const int*  node_order   = (const int*)d_in[3];
    const void* work         = d_in[4];
    const void* subtask      = d_in[5];
    const void* W_heads      = d_in[6];
    const void* a_heads      = d_in[7];
    const void* W_out        = d_in[8];
    const void* a_out        = d_in[9];
    const void* fc1w         = d_in[10];
    const void* fc1b         = d_in[11];
    const void* fc2w         = d_in[12];
    const void* fc2b         = d_in[13];
    const void* fc3w         = d_in[14];
    const void* fc3b         = d_in[15];

    prep_kernel<<<dim3(1318), dim3(256), 0, stream>>>(graph_matrix, W_heads, W_out, graph_inf,
                                                      fc1w, fc2w, fc3w, masks);
    gemm1_kernel<<<dim3(4, 128), dim3(256), 0, stream>>>(graph_inf, a_heads, masks);
    att1_kernel<<<dim3(512), dim3(512), 0, stream>>>(masks);
    gemm2_kernel<<<dim3(256), dim3(256), 0, stream>>>(a_out, masks);
    fin_att<<<dim3(32), dim3(256), 0, stream>>>(masks, node_order, work, subtask);
    mlp1_kernel<<<dim3(4), dim3(256), 0, stream>>>(fc1b, masks);
    mlp2_kernel<<<dim3(4), dim3(256), 0, stream>>>(fc2b, masks);
    mlp3_kernel<<<dim3(8), dim3(256), 0, stream>>>(fc3b, masks);
    softmax_kernel<<<dim3(32), dim3(64), 0, stream>>>(masks, d_out);
}

// Round 13
// 183.098 us; speedup vs baseline: 1.0485x; 1.0485x over previous
//
#include <hip/hip_runtime.h>

typedef unsigned short u16;
typedef unsigned int u32;
typedef unsigned long long u64;

typedef __bf16 bf16x8 __attribute__((ext_vector_type(8)));
typedef float f32x4 __attribute__((ext_vector_type(4)));

#define LOG2E 1.44269504088896340736f

__device__ __forceinline__ float b2f(u16 u) {
    u32 x = ((u32)u) << 16;
    return __builtin_bit_cast(float, x);
}
__device__ __forceinline__ u16 f2b(float f) {
    u32 u = __builtin_bit_cast(u32, f);
    u32 r = (u + 0x7fffu + ((u >> 16) & 1u)) >> 16;
    return (u16)r;
}
__device__ __forceinline__ float ld(const void* p, int i, bool bf) {
    return bf ? b2f(((const u16*)p)[i]) : ((const float*)p)[i];
}
__device__ __forceinline__ bool detect_bf16(const void* masks) {
    return ((const u16*)masks)[0] != 0;
}
__device__ __forceinline__ f32x4 mfma16(bf16x8 a, bf16x8 b, f32x4 c) {
    return __builtin_amdgcn_mfma_f32_16x16x32_bf16(a, b, c, 0, 0, 0);
}

// ---------------- device-global scratch ----------------
__device__ __attribute__((aligned(256))) u32  g_adjm[16384 * 16];   // bitmask
__device__ __attribute__((aligned(256))) u16  g_BT1[512 * 128];     // W_heads^T [h*64+o][k]
__device__ __attribute__((aligned(256))) u16  g_BT2[128 * 512];     // W_out^T
__device__ __attribute__((aligned(256))) u16  g_Xc[32 * 512 * 128]; // bf16 graph_inf (f32 case)
__device__ __attribute__((aligned(256))) u16  g_xb[16384 * 512];    // concat ELU output
__device__ __attribute__((aligned(256))) u16  g_Wh2[16384 * 128];   // out-layer features
__device__ __attribute__((aligned(256))) float g_s1b[16384];        // x log2e
__device__ __attribute__((aligned(256))) float g_s2b[16384];
__device__ __attribute__((aligned(256))) u16  g_fc1T[256 * 192];
__device__ __attribute__((aligned(256))) u16  g_fc2T[256 * 256];
__device__ __attribute__((aligned(256))) u16  g_fc3T[512 * 256];
__device__ __attribute__((aligned(256))) u16  g_Ahi[32 * 192];
__device__ __attribute__((aligned(256))) u16  g_Alo[32 * 192];
__device__ __attribute__((aligned(256))) u16  g_H1hi[32 * 256];
__device__ __attribute__((aligned(256))) u16  g_H1lo[32 * 256];
__device__ __attribute__((aligned(256))) u16  g_H2hi[32 * 256];
__device__ __attribute__((aligned(256))) u16  g_H2lo[32 * 256];
__device__ __attribute__((aligned(256))) float g_logits[32 * 512];

// ---------------------------------------------------------------------------
// PREP: adj -> bitmask (ballot-free, 8-deep MLP); weight transposes; Xc cast.
// ---------------------------------------------------------------------------
__global__ __launch_bounds__(256) void prep_kernel(
    const int* __restrict__ adj, const void* __restrict__ Whd,
    const void* __restrict__ Wo, const void* __restrict__ Xin,
    const void* __restrict__ fc1w, const void* __restrict__ fc2w,
    const void* __restrict__ fc3w, const void* __restrict__ masks)
{
    const bool bf = detect_bf16(masks);
    const int blk = blockIdx.x;
    const int tid = threadIdx.x;
    if (blk < 1024) {
        int id = blk * 256 + tid;
        int row = id >> 4, w = id & 15;
        const int4* p = (const int4*)(adj + row * 512 + w * 32);
        int4 v[8];
        #pragma unroll
        for (int s = 0; s < 8; ++s) v[s] = p[s];
        u32 word = 0;
        #pragma unroll
        for (int s = 0; s < 8; ++s) {
            u32 nib = (v[s].x > 0 ? 1u : 0u) | (v[s].y > 0 ? 2u : 0u) |
                      (v[s].z > 0 ? 4u : 0u) | (v[s].w > 0 ? 8u : 0u);
            word |= nib << (4 * s);
        }
        g_adjm[id] = word;
    } else if (blk < 1028) {
        int base = (blk - 1024) * 16384;
        for (int e = base + tid; e < base + 16384; e += 256) {
            int n = e >> 7, k = e & 127;           // BT1[n][k] = W_heads[h][k][o]
            g_BT1[e] = f2b(ld(Whd, (n >> 6) * 8192 + k * 64 + (n & 63), bf));
        }
    } else if (blk < 1032) {
        int base = (blk - 1028) * 16384;
        for (int e = base + tid; e < base + 16384; e += 256) {
            int n = e >> 9, k = e & 511;           // BT2[n][k] = W_out[k][n]
            g_BT2[e] = f2b(ld(Wo, k * 128 + n, bf));
        }
    } else if (blk < 1288) {
        if (!bf) {
            int base = (blk - 1032) * 8192;
            for (int e = base + tid; e < base + 8192; e += 256)
                g_Xc[e] = f2b(((const float*)Xin)[e]);
        }
    } else if (blk < 1294) {                       // fc1T: 256x192
        int base = (blk - 1288) * 8192;
        for (int e = base + tid; e < base + 8192; e += 256) {
            int n = e / 192, k = e - n * 192;
            g_fc1T[e] = f2b(ld(fc1w, k * 256 + n, bf));
        }
    } else if (blk < 1302) {                       // fc2T: 256x256
        int base = (blk - 1294) * 8192;
        for (int e = base + tid; e < base + 8192; e += 256) {
            int n = e >> 8, k = e & 255;
            g_fc2T[e] = f2b(ld(fc2w, k * 256 + n, bf));
        }
    } else {                                       // fc3T: 512x256
        int base = (blk - 1302) * 8192;
        for (int e = base + tid; e < base + 8192; e += 256) {
            int n = e >> 8, k = e & 255;
            g_fc3T[e] = f2b(ld(fc3w, k * 512 + n, bf));
        }
    }
}

// ---------------------------------------------------------------------------
// GAT1 v2 (fused gemm1 + scores + attention): 256 blocks x 1024 threads
// (16 waves = 4 waves/SIMD). b = blockIdx&31, h = blockIdx>>5 so all 8
// h-blocks of a batch share one XCD (XCD = blockIdx%8) -> Xc/adj fetched
// once per XCD L2. Phase 1: Wh = BT1_h @ Xc[b]^T chunk-wise into LDS
// (register-prefetched staging); s1/s2 fp32 partials in LDS.
// Phase 2: attention, each wave owns 32 rows (2 groups).
// [R11 config -- measured best 185.8 us; R12's split regressed to 192.0]
// ---------------------------------------------------------------------------
__global__ __launch_bounds__(1024, 1) void gat1_kernel(
    const void* __restrict__ Xin, const void* __restrict__ a_heads,
    const void* __restrict__ masks)
{
    __shared__ __attribute__((aligned(16))) u16 WhL[64 * 520];   // [o][node]
    __shared__ __attribute__((aligned(16))) u16 As[64 * 136];    // BT1 h-slice
    __shared__ __attribute__((aligned(16))) u16 XcL[128 * 136];  // node chunk
    __shared__ float s1p[4][512];
    __shared__ float s2p[4][512];
    __shared__ float E2s[512];
    __shared__ float E2ps[512];

    const bool bf = detect_bf16(masks);
    const int tid = threadIdx.x;
    const int w = tid >> 6, lane = tid & 63;
    const int c = lane & 15, q = lane >> 4;
    const int b = blockIdx.x & 31;
    const int h = blockIdx.x >> 5;

    const u16* Bsrc = bf ? (const u16*)Xin : g_Xc;   // [b*512+n][128]

    // stage As: BT1 rows h*64+r (64 rows x 128 k); 1024 thr -> 1 uint4 each
    {
        int r = tid >> 4, seg = (tid & 15) * 8;
        *(uint4*)&As[r * 136 + seg] = *(const uint4*)(g_BT1 + (h * 64 + r) * 128 + seg);
    }

    // Phase 1: 4 node-chunks of 128; wave = (wm feature-tile, wn node-32-slice)
    const int wm = w & 3, wn = w >> 2;
    float a1v[4], a2v[4];
    #pragma unroll
    for (int i = 0; i < 4; ++i) {
        int o = wm * 16 + q * 4 + i;
        a1v[i] = ld(a_heads, h * 128 + o, bf);
        a2v[i] = ld(a_heads, h * 128 + 64 + o, bf);
    }

    // register prefetch: each thread owns 16 u16 of the chunk (r = tid>>3)
    const int pr = tid >> 3, pseg = (tid & 7) * 16;
    uint4 xr0, xr1;
    {
        const u16* src = Bsrc + (b * 512 + pr) * 128 + pseg;
        xr0 = *(const uint4*)src;
        xr1 = *(const uint4*)(src + 8);
    }

    for (int chunk = 0; chunk < 4; ++chunk) {
        __syncthreads();   // XcL free (prior MFMA reads done) / As ready gate below
        *(uint4*)&XcL[pr * 136 + pseg] = xr0;
        *(uint4*)&XcL[pr * 136 + pseg + 8] = xr1;
        if (chunk < 3) {   // issue next chunk's loads now; they drain during MFMA
            const u16* src = Bsrc + (b * 512 + (chunk + 1) * 128 + pr) * 128 + pseg;
            xr0 = *(const uint4*)src;
            xr1 = *(const uint4*)(src + 8);
        }
        __syncthreads();   // XcL (and on chunk 0, As) ready
        f32x4 cacc[2] = {};
        #pragma unroll
        for (int kt = 0; kt < 4; ++kt) {
            bf16x8 af = *(const bf16x8*)&As[(wm * 16 + c) * 136 + kt * 32 + q * 8];
            #pragma unroll
            for (int nt = 0; nt < 2; ++nt) {
                bf16x8 bv = *(const bf16x8*)&XcL[(wn * 32 + nt * 16 + c) * 136 + kt * 32 + q * 8];
                cacc[nt] = mfma16(af, bv, cacc[nt]);
            }
        }
        // write WhL (bf16) + s1/s2 fp32 partials for this feature tile
        #pragma unroll
        for (int nt = 0; nt < 2; ++nt) {
            const int ncol = chunk * 128 + wn * 32 + nt * 16 + c;
            float p1 = 0.f, p2 = 0.f;
            #pragma unroll
            for (int i = 0; i < 4; ++i) {
                float v = cacc[nt][i];
                WhL[(wm * 16 + q * 4 + i) * 520 + ncol] = f2b(v);
                p1 += v * a1v[i];
                p2 += v * a2v[i];
            }
            p1 += __shfl_xor(p1, 16); p1 += __shfl_xor(p1, 32);
            p2 += __shfl_xor(p2, 16); p2 += __shfl_xor(p2, 32);
            if (lane < 16) {
                int n = chunk * 128 + wn * 32 + nt * 16 + lane;
                s1p[wm][n] = p1;
                s2p[wm][n] = p2;
            }
        }
    }
    __syncthreads();
    // E2 tables from summed partials
    {
        int j = tid & 511;
        float s2v = (s2p[0][j] + s2p[1][j] + s2p[2][j] + s2p[3][j]) * LOG2E;
        if (tid < 512) E2s[j]  = exp2f(s2v);
        else           E2ps[j] = exp2f(0.2f * s2v);
    }
    __syncthreads();

    // Phase 2: wave owns rows w*32 + g*16 + c, g in {0,1}
    const u32* adjb = g_adjm + b * 8192;
    const u32 bword = (c == 0) ? 0x3F803F80u : 0u;
    const uint4 bq = {bword, bword, bword, bword};
    const bf16x8 bone = __builtin_bit_cast(bf16x8, bq);

    float E1[2], E1p[2];
    #pragma unroll
    for (int g = 0; g < 2; ++g) {
        int r = w * 32 + g * 16 + c;
        float s1v = (s1p[0][r] + s1p[1][r] + s1p[2][r] + s1p[3][r]) * LOG2E;
        E1[g]  = exp2f(s1v);
        E1p[g] = exp2f(0.2f * s1v);
    }

    f32x4 acc[2][4] = {};
    f32x4 acc1[2] = {};
    const u16* lbase = &WhL[c * 520 + q * 8];

    for (int kc = 0; kc < 4; ++kc) {
        union { uint4 v; u32 a[4]; } wq[2];
        #pragma unroll
        for (int g = 0; g < 2; ++g)
            wq[g].v = *(const uint4*)(adjb + (w * 32 + g * 16 + c) * 16 + kc * 4);
        #pragma unroll
        for (int tl = 0; tl < 4; ++tl) {
            const int jb = kc * 128 + tl * 32 + q * 8;
            union { float4 v[2]; float f[8]; } e2r, e2pr;
            e2r.v[0]  = *(const float4*)&E2s[jb];
            e2r.v[1]  = *(const float4*)&E2s[jb + 4];
            e2pr.v[0] = *(const float4*)&E2ps[jb];
            e2pr.v[1] = *(const float4*)&E2ps[jb + 4];
            bf16x8 bfrag[4];
            #pragma unroll
            for (int nt = 0; nt < 4; ++nt)
                bfrag[nt] = *(const bf16x8*)(lbase + nt * 16 * 520 + kc * 128 + tl * 32);
            #pragma unroll
            for (int g = 0; g < 2; ++g) {
                u32 wbits = wq[g].a[tl] >> (q * 8);
                u32 pk[4];
                #pragma unroll
                for (int pi = 0; pi < 4; ++pi) {
                    float z0 = fmaxf(E1[g] * e2r.f[2 * pi],     E1p[g] * e2pr.f[2 * pi]);
                    float z1 = fmaxf(E1[g] * e2r.f[2 * pi + 1], E1p[g] * e2pr.f[2 * pi + 1]);
                    z0 = ((wbits >> (2 * pi)) & 1u) ? z0 : 0.f;
                    z1 = ((wbits >> (2 * pi + 1)) & 1u) ? z1 : 0.f;
                    pk[pi] = __builtin_amdgcn_perm(__builtin_bit_cast(u32, z1),
                                                   __builtin_bit_cast(u32, z0),
                                                   0x07060302u);
                }
                uint4 pkv = {pk[0], pk[1], pk[2], pk[3]};
                bf16x8 pv = __builtin_bit_cast(bf16x8, pkv);
                acc1[g] = mfma16(pv, bone, acc1[g]);
                #pragma unroll
                for (int nt = 0; nt < 4; ++nt)
                    acc[g][nt] = mfma16(pv, bfrag[nt], acc[g][nt]);
            }
        }
    }
    #pragma unroll
    for (int g = 0; g < 2; ++g) {
        const int R = w * 32 + g * 16;
        #pragma unroll
        for (int i = 0; i < 4; ++i) {
            float lr = __shfl(acc1[g][i], (lane & 48));
            float invr = (lr == 0.f) ? (1.f / 512.f) : (1.f / lr);
            const int row = R + q * 4 + i;
            float mk = ld(masks, b * 512 + row, bf);
            #pragma unroll
            for (int nt = 0; nt < 4; ++nt) {
                float v = acc[g][nt][i] * invr * mk;
                float o = v > 0.f ? v : (__expf(v) - 1.f);
                g_xb[(b * 512 + row) * 512 + h * 64 + nt * 16 + c] = f2b(o);
            }
        }
    }
}

// ---------------------------------------------------------------------------
// GEMM2: Wh2[16384x128] = xb @ BT2^T. BM=64, grid 256. s1b/s2b epilogue.
// ---------------------------------------------------------------------------
__global__ __launch_bounds__(256, 2) void gemm2_kernel(
    const void* __restrict__ a_out, const void* __restrict__ masks)
{
    __shared__ __attribute__((aligned(16))) u16 Asl[64 * 72];
    __shared__ __attribute__((aligned(16))) u16 Bsl[128 * 72];
    const int tid = threadIdx.x;
    const int w = tid >> 6, lane = tid & 63;
    const int c = lane & 15, q = lane >> 4;
    const int tm = blockIdx.x * 64;
    const int rowA = tid >> 2, shA = (tid & 3) * 16;
    const int rowB = tid >> 1, shB = (tid & 1) * 32;
    f32x4 acc[8] = {};
    for (int kc = 0; kc < 512; kc += 64) {
        __syncthreads();
        const u16* Ag = g_xb + (tm + rowA) * 512 + kc + shA;
        *(uint4*)&Asl[rowA * 72 + shA] = *(const uint4*)Ag;
        *(uint4*)&Asl[rowA * 72 + shA + 8] = *(const uint4*)(Ag + 8);
        const u16* Bg = g_BT2 + rowB * 512 + kc + shB;
        #pragma unroll
        for (int s = 0; s < 4; ++s)
            *(uint4*)&Bsl[rowB * 72 + shB + 8 * s] = *(const uint4*)(Bg + 8 * s);
        __syncthreads();
        #pragma unroll
        for (int kt = 0; kt < 2; ++kt) {
            bf16x8 av = *(const bf16x8*)&Asl[(w * 16 + c) * 72 + kt * 32 + q * 8];
            #pragma unroll
            for (int ct = 0; ct < 8; ++ct) {
                bf16x8 bv = *(const bf16x8*)&Bsl[(ct * 16 + c) * 72 + kt * 32 + q * 8];
                acc[ct] = mfma16(av, bv, acc[ct]);
            }
        }
    }
    const bool bf = detect_bf16(masks);
    float a1v[8], a2v[8];
    #pragma unroll
    for (int ct = 0; ct < 8; ++ct) {
        a1v[ct] = ld(a_out, ct * 16 + c, bf);
        a2v[ct] = ld(a_out, 128 + ct * 16 + c, bf);
    }
    #pragma unroll
    for (int i = 0; i < 4; ++i) {
        float p1 = 0.f, p2 = 0.f;
        #pragma unroll
        for (int ct = 0; ct < 8; ++ct) {
            p1 += acc[ct][i] * a1v[ct];
            p2 += acc[ct][i] * a2v[ct];
        }
        #pragma unroll
        for (int off = 1; off < 16; off <<= 1) {
            p1 += __shfl_xor(p1, off);
            p2 += __shfl_xor(p2, off);
        }
        if (c == 0) {
            int m = tm + w * 16 + q * 4 + i;
            g_s1b[m] = p1 * LOG2E;
            g_s2b[m] = p2 * LOG2E;
        }
    }
    #pragma unroll
    for (int ct = 0; ct < 8; ++ct)
        #pragma unroll
        for (int i = 0; i < 4; ++i) {
            int m = tm + w * 16 + q * 4 + i;
            g_Wh2[m * 128 + ct * 16 + c] = f2b(acc[ct][i]);
        }
}

// ---------------------------------------------------------------------------
// FIN_ATT: block per b. Selected-row attention; writes hi/lo MLP input.
// ---------------------------------------------------------------------------
__global__ __launch_bounds__(256) void fin_att(
    const void* __restrict__ masks, const int* __restrict__ node_order,
    const void* __restrict__ workv, const void* __restrict__ subtaskv)
{
    __shared__ float att[512];
    __shared__ float parts[16][128];
    __shared__ float redl[4];

    const bool bf = detect_bf16(masks);
    const int b = blockIdx.x, t = threadIdx.x;
    const int lane = t & 63, wv = t >> 6;
    const int istar = node_order[b];

    const float s1v = g_s1b[b * 512 + istar];
    const u32* arow = g_adjm + (b * 512 + istar) * 16;
    float ssum = 0.f;
    #pragma unroll
    for (int rep = 0; rep < 2; ++rep) {
        int j = t + rep * 256;
        float e = s1v + g_s2b[b * 512 + j];
        e = fmaxf(e, 0.2f * e);
        float ex = ((arow[j >> 5] >> (j & 31)) & 1u) ? exp2f(e) : 0.f;
        att[j] = ex;
        ssum += ex;
    }
    for (int off = 1; off < 64; off <<= 1) ssum += __shfl_xor(ssum, off);
    if (lane == 0) redl[wv] = ssum;
    __syncthreads();
    float tot = redl[0] + redl[1] + redl[2] + redl[3];
    bool uni = (tot == 0.f);
    float inv = uni ? (1.f / 512.f) : (1.f / tot);

    const int og = t & 15, jg = t >> 4;
    float acc[8] = {};
    const u16* base = g_Wh2 + (b * 512 + jg * 32) * 128 + og * 8;
    #pragma unroll 8
    for (int j0 = 0; j0 < 32; ++j0) {
        float wgt = uni ? 1.f : att[jg * 32 + j0];
        union { u16 u[8]; uint4 v; } z;
        z.v = *(const uint4*)(base + j0 * 128);
        #pragma unroll
        for (int i = 0; i < 8; ++i) acc[i] += wgt * b2f(z.u[i]);
    }
    #pragma unroll
    for (int i = 0; i < 8; ++i) parts[jg][og * 8 + i] = acc[i];
    __syncthreads();
    float mk = ld(masks, b * 512 + istar, bf);
    if (t < 128) {
        float s = 0.f;
        #pragma unroll
        for (int jj = 0; jj < 16; ++jj) s += parts[jj][t];
        s *= inv * mk * mk;
        u16 hi = f2b(s);
        g_Ahi[b * 192 + t] = hi;
        g_Alo[b * 192 + t] = f2b(s - b2f(hi));
    } else if (t < 160) {
        g_Ahi[b * 192 + t] = bf ? ((const u16*)workv)[b * 32 + t - 128]
                                : f2b(((const float*)workv)[b * 32 + t - 128]);
        g_Alo[b * 192 + t] = 0;
    } else if (t < 192) {
        g_Ahi[b * 192 + t] = bf ? ((const u16*)subtaskv)[b * 32 + t - 160]
                                : f2b(((const float*)subtaskv)[b * 32 + t - 160]);
        g_Alo[b * 192 + t] = 0;
    }
}

// ---------------------------------------------------------------------------
// MLP layer body: wave w owns 16 output cols; direct global loads, no LDS.
// Wrappers bind device-global scratch IN DEVICE CODE.
// ---------------------------------------------------------------------------
template<int K, int NOUT, bool RELU>
__device__ __forceinline__ void mlp_body(
    const u16* __restrict__ Ahi, const u16* __restrict__ Alo,
    const u16* __restrict__ WT, const void* __restrict__ bias,
    u16* __restrict__ Ohi, u16* __restrict__ Olo, float* __restrict__ Of,
    const void* __restrict__ masks)
{
    const bool bf = detect_bf16(masks);
    const int t = threadIdx.x, w = t >> 6, lane = t & 63;
    const int c = lane & 15, q = lane >> 4;
    const int col = blockIdx.x * 64 + w * 16 + c;

    const u16* wp  = WT + col * K + q * 8;
    const u16* ahp = Ahi + c * K + q * 8;
    const u16* alp = Alo + c * K + q * 8;

    f32x4 acc0 = {}, acc1 = {};
    #pragma unroll
    for (int kt = 0; kt < K / 32; ++kt) {
        bf16x8 bw  = *(const bf16x8*)(wp + kt * 32);
        bf16x8 ah0 = *(const bf16x8*)(ahp + kt * 32);
        bf16x8 al0 = *(const bf16x8*)(alp + kt * 32);
        bf16x8 ah1 = *(const bf16x8*)(ahp + 16 * K + kt * 32);
        bf16x8 al1 = *(const bf16x8*)(alp + 16 * K + kt * 32);
        acc0 = mfma16(ah0, bw, acc0);
        acc0 = mfma16(al0, bw, acc0);
        acc1 = mfma16(ah1, bw, acc1);
        acc1 = mfma16(al1, bw, acc1);
    }
    float bs = ld(bias, col, bf);
    #pragma unroll
    for (int mt = 0; mt < 2; ++mt) {
        f32x4 a = mt ? acc1 : acc0;
        #pragma unroll
        for (int i = 0; i < 4; ++i) {
            int m = mt * 16 + q * 4 + i;
            float v = a[i] + bs;
            if (RELU) {
                v = fmaxf(v, 0.f);
                u16 hi = f2b(v);
                Ohi[m * NOUT + col] = hi;
                Olo[m * NOUT + col] = f2b(v - b2f(hi));
            } else {
                Of[m * NOUT + col] = v;
            }
        }
    }
}

__global__ __launch_bounds__(256) void mlp1_kernel(const void* bias, const void* masks) {
    mlp_body<192, 256, true>(g_Ahi, g_Alo, g_fc1T, bias, g_H1hi, g_H1lo, nullptr, masks);
}
__global__ __launch_bounds__(256) void mlp2_kernel(const void* bias, const void* masks) {
    mlp_body<256, 256, true>(g_H1hi, g_H1lo, g_fc2T, bias, g_H2hi, g_H2lo, nullptr, masks);
}
__global__ __launch_bounds__(256) void mlp3_kernel(const void* bias, const void* masks) {
    mlp_body<256, 512, false>(g_H2hi, g_H2lo, g_fc3T, bias, nullptr, nullptr, g_logits, masks);
}

// ---------------------------------------------------------------------------
// SOFTMAX: 32 blocks (one per batch row) x 64 lanes; 8 logits per lane.
// ---------------------------------------------------------------------------
__global__ __launch_bounds__(64) void softmax_kernel(
    const void* __restrict__ masks, void* __restrict__ out)
{
    const bool bf = detect_bf16(masks);
    const int row = blockIdx.x, lane = threadIdx.x;
    const float* lp = g_logits + row * 512 + lane * 8;
    float v[8];
    *(float4*)&v[0] = *(const float4*)lp;
    *(float4*)&v[4] = *(const float4*)(lp + 4);
    float mx = v[0];
    #pragma unroll
    for (int i = 1; i < 8; ++i) mx = fmaxf(mx, v[i]);
    for (int off = 1; off < 64; off <<= 1) mx = fmaxf(mx, __shfl_xor(mx, off));
    float e[8];
    float s = 0.f;
    #pragma unroll
    for (int i = 0; i < 8; ++i) { e[i] = __expf(v[i] - mx); s += e[i]; }
    for (int off = 1; off < 64; off <<= 1) s += __shfl_xor(s, off);
    float inv = 1.f / s;
    if (bf) {
        u16* o = (u16*)out + row * 512 + lane * 8;
        #pragma unroll
        for (int i = 0; i < 8; ++i) o[i] = f2b(e[i] * inv);
    } else {
        float* o = (float*)out + row * 512 + lane * 8;
        #pragma unroll
        for (int i = 0; i < 8; ++i) o[i] = e[i] * inv;
    }
}

// ---------------------------------------------------------------------------
extern "C" void kernel_launch(void* const* d_in, const int* in_sizes, int n_in,
                              void* d_out, int out_size, void* d_ws, size_t ws_size,
                              hipStream_t stream)
{
    const void* graph_inf    = d_in[0];
    const int*  graph_matrix = (const int*)d_in[1];
    const void* masks        = d_in[2];
    const int*  node_order   = (const int*)d_in[3];
    const void* work         = d_in[4];
    const void* subtask      = d_in[5];
    const void* W_heads      = d_in[6];
    const void* a_heads      = d_in[7];
    const void* W_out        = d_in[8];
    const void* a_out        = d_in[9];
    const void* fc1w         = d_in[10];
    const void* fc1b         = d_in[11];
    const void* fc2w         = d_in[12];
    const void* fc2b         = d_in[13];
    const void* fc3w         = d_in[14];
    const void* fc3b         = d_in[15];

    prep_kernel<<<dim3(1318), dim3(256), 0, stream>>>(graph_matrix, W_heads, W_out, graph_inf,
                                                      fc1w, fc2w, fc3w, masks);
    gat1_kernel<<<dim3(256), dim3(1024), 0, stream>>>(graph_inf, a_heads, masks);
    gemm2_kernel<<<dim3(256), dim3(256), 0, stream>>>(a_out, masks);
    fin_att<<<dim3(32), dim3(256), 0, stream>>>(masks, node_order, work, subtask);
    mlp1_kernel<<<dim3(4), dim3(256), 0, stream>>>(fc1b, masks);
    mlp2_kernel<<<dim3(4), dim3(256), 0, stream>>>(fc2b, masks);
    mlp3_kernel<<<dim3(8), dim3(256), 0, stream>>>(fc3b, masks);
    softmax_kernel<<<dim3(32), dim3(64), 0, stream>>>(masks, d_out);
}